// Round 1
// baseline (49.328 us; speedup 1.0000x reference)
//
#include <hip/hip_runtime.h>
#include <hip/hip_bf16.h>

// ---------------------------------------------------------------------------
// Problem: scores[y,x] = sum_h W2[h] * ( sum_{m,n} leaky( py[y,h,m,:].px[x,h,n,:] / 8 ) ) / (nItem[x]*64)
//   py = (Y @ W1) split heads          [96,2,64,64]
//   px = (gelu(X @ Wp) @ W1) heads     [96,2,48,64]
// Strategy: prep kernels emit py/px as bf16 in MFMA *fragment order* so the
// main pairwise kernel is pure coalesced global loads + register MFMA.
// leaky(z) = 0.3 z + 0.7 relu(z); positive scales deferred to the epilogue.
// ---------------------------------------------------------------------------

typedef short bf16x8 __attribute__((ext_vector_type(8))); // 8 bf16 = 4 VGPRs
typedef float f32x4 __attribute__((ext_vector_type(4)));

__device__ __forceinline__ unsigned short f2bf(float v) {
  __hip_bfloat16 b = __float2bfloat16(v);
  return *reinterpret_cast<unsigned short*>(&b);
}

// ---------------------------------------------------------------------------
// K1: gallery[4608,64] = gelu_exact(X[4608,512] @ Wp[512,64])
// block = 256 thr = 64 cols x 4 row-quads; 16 rows/block -> 288 blocks.
// Row loads are wave-uniform (readfirstlane) -> scalar loads; Wp coalesced.
// ---------------------------------------------------------------------------
__global__ __launch_bounds__(256) void k_gallery(const float* __restrict__ x,
                                                 const float* __restrict__ Wp,
                                                 float* __restrict__ g) {
  int t = threadIdx.x;
  int c = t & 63;
  int rq = __builtin_amdgcn_readfirstlane(t >> 6); // 0..3, wave-uniform
  int row0 = blockIdx.x * 16 + rq * 4;
  const float* xr = x + (size_t)row0 * 512;
  float a0 = 0.f, a1 = 0.f, a2 = 0.f, a3 = 0.f;
#pragma unroll 8
  for (int k = 0; k < 512; ++k) {
    float w = Wp[k * 64 + c];
    a0 = fmaf(xr[k], w, a0);
    a1 = fmaf(xr[512 + k], w, a1);
    a2 = fmaf(xr[1024 + k], w, a2);
    a3 = fmaf(xr[1536 + k], w, a3);
  }
  float av[4] = {a0, a1, a2, a3};
#pragma unroll
  for (int j = 0; j < 4; ++j) {
    float v = av[j];
    // exact gelu: x * 0.5 * (1 + erf(x/sqrt(2)))
    float ge = 0.5f * v * (1.0f + erff(v * 0.70710678118654752f));
    g[(size_t)(row0 + j) * 64 + c] = ge;
  }
}

// ---------------------------------------------------------------------------
// Fragment layout (both operands of mfma_f32_16x16x32_bf16 use the same map):
//   lane l holds element (rc = l&15, k = 8*(l>>4)+i), i=0..7 packed.
// py image: [y][h][mt(4)][kc(2)][lane(64)][i(8)]  -> 512 bf16 per frag
// px image: [x][h][nt(3)][kc(2)][lane(64)][i(8)]
// ---------------------------------------------------------------------------

// K2: py = Y[6144,64] @ W1[64,128] -> bf16 fragment image.
// block = 256 thr = 128 d x 2 row-quads; 8 rows/block -> 768 blocks.
__global__ __launch_bounds__(256) void k_pyf(const float* __restrict__ y,
                                             const float* __restrict__ W1,
                                             unsigned short* __restrict__ pyf) {
  int t = threadIdx.x;
  int d = t & 127;
  int rq = __builtin_amdgcn_readfirstlane(t >> 7); // 0..1, wave-uniform
  int row0 = blockIdx.x * 8 + rq * 4;
  const float* yr = y + (size_t)row0 * 64;
  float a0 = 0.f, a1 = 0.f, a2 = 0.f, a3 = 0.f;
#pragma unroll 8
  for (int k = 0; k < 64; ++k) {
    float w = W1[k * 128 + d];
    a0 = fmaf(yr[k], w, a0);
    a1 = fmaf(yr[64 + k], w, a1);
    a2 = fmaf(yr[128 + k], w, a2);
    a3 = fmaf(yr[192 + k], w, a3);
  }
  float av[4] = {a0, a1, a2, a3};
  int h = d >> 6, dd = d & 63;
  int kc = dd >> 5, q = (dd >> 3) & 3, i = dd & 7;
#pragma unroll
  for (int j = 0; j < 4; ++j) {
    int row = row0 + j;
    int yi = row >> 6, m = row & 63;
    int mt = m >> 4, r = m & 15;
    int l = r + (q << 4);
    size_t idx = ((size_t)((yi * 2 + h) * 8 + mt * 2 + kc)) * 512 + l * 8 + i;
    pyf[idx] = f2bf(av[j]);
  }
}

// K3: px = gallery[4608,64] @ W1[64,128] -> bf16 fragment image (48 rows/x).
__global__ __launch_bounds__(256) void k_pxf(const float* __restrict__ g,
                                             const float* __restrict__ W1,
                                             unsigned short* __restrict__ pxf) {
  int t = threadIdx.x;
  int d = t & 127;
  int rq = __builtin_amdgcn_readfirstlane(t >> 7);
  int row0 = blockIdx.x * 8 + rq * 4;
  const float* gr = g + (size_t)row0 * 64;
  float a0 = 0.f, a1 = 0.f, a2 = 0.f, a3 = 0.f;
#pragma unroll 8
  for (int k = 0; k < 64; ++k) {
    float w = W1[k * 128 + d];
    a0 = fmaf(gr[k], w, a0);
    a1 = fmaf(gr[64 + k], w, a1);
    a2 = fmaf(gr[128 + k], w, a2);
    a3 = fmaf(gr[192 + k], w, a3);
  }
  float av[4] = {a0, a1, a2, a3};
  int h = d >> 6, dd = d & 63;
  int kc = dd >> 5, q = (dd >> 3) & 3, i = dd & 7;
#pragma unroll
  for (int j = 0; j < 4; ++j) {
    int row = row0 + j;
    int xi = row / 48, n = row % 48;
    int nt = n >> 4, r = n & 15;
    int l = r + (q << 4);
    size_t idx = ((size_t)((xi * 2 + h) * 6 + nt * 2 + kc)) * 512 + l * 8 + i;
    pxf[idx] = f2bf(av[j]);
  }
}

// ---------------------------------------------------------------------------
// K4: main pairwise kernel. One wave per (y,x) pair; block = 4 waves sharing y
// (L1 reuse of the py panel). 2304 blocks. Per wave per head: 14 coalesced
// 16B/lane frag loads -> 24 register MFMAs -> inline leaky reduction.
// ---------------------------------------------------------------------------
__global__ __launch_bounds__(256) void k_att(const unsigned short* __restrict__ pyf_u,
                                             const unsigned short* __restrict__ pxf_u,
                                             const float* __restrict__ nItem,
                                             const float* __restrict__ W2,
                                             float* __restrict__ out) {
  int t = threadIdx.x;
  int lane = t & 63;
  int w = t >> 6;
  int bid = blockIdx.x;
  int yi = bid / 24;
  int xi = (bid % 24) * 4 + w;

  const bf16x8* PA = reinterpret_cast<const bf16x8*>(pyf_u);
  const bf16x8* PB = reinterpret_cast<const bf16x8*>(pxf_u);

  float sh0 = 0.f, sh1 = 0.f;
#pragma unroll
  for (int h = 0; h < 2; ++h) {
    bf16x8 a[4][2], b[3][2];
    size_t ab = (size_t)(yi * 2 + h) * 512 + lane; // panel = 8 frags * 64 units
    size_t bb = (size_t)(xi * 2 + h) * 384 + lane; // panel = 6 frags * 64 units
#pragma unroll
    for (int mt = 0; mt < 4; ++mt) {
      a[mt][0] = PA[ab + (mt * 2 + 0) * 64];
      a[mt][1] = PA[ab + (mt * 2 + 1) * 64];
    }
#pragma unroll
    for (int nt = 0; nt < 3; ++nt) {
      b[nt][0] = PB[bb + (nt * 2 + 0) * 64];
      b[nt][1] = PB[bb + (nt * 2 + 1) * 64];
    }
    float sz = 0.f, sr = 0.f;
#pragma unroll
    for (int nt = 0; nt < 3; ++nt) {
#pragma unroll
      for (int mt = 0; mt < 4; ++mt) {
        f32x4 acc = {0.f, 0.f, 0.f, 0.f};
        acc = __builtin_amdgcn_mfma_f32_16x16x32_bf16(a[mt][0], b[nt][0], acc, 0, 0, 0);
        acc = __builtin_amdgcn_mfma_f32_16x16x32_bf16(a[mt][1], b[nt][1], acc, 0, 0, 0);
#pragma unroll
        for (int j = 0; j < 4; ++j) {
          sz += acc[j];
          sr += fmaxf(acc[j], 0.f);
        }
      }
    }
    float s = 0.3f * sz + 0.7f * sr; // sum of leaky over raw scores
    if (h == 0) sh0 = s; else sh1 = s;
  }
  // full-wave reduction
#pragma unroll
  for (int off = 32; off >= 1; off >>= 1) {
    sh0 += __shfl_xor(sh0, off, 64);
    sh1 += __shfl_xor(sh1, off, 64);
  }
  if (lane == 0) {
    // deferred scales: 1/sqrt(64)=1/8 (pre-leaky, commutes) and 1/(nItem*Ny)
    float inv = 1.0f / (8.0f * 64.0f * nItem[xi]);
    out[yi * 96 + xi] = (sh0 * W2[0] + sh1 * W2[1]) * inv;
  }
}

// ---------------------------------------------------------------------------
extern "C" void kernel_launch(void* const* d_in, const int* in_sizes, int n_in,
                              void* d_out, int out_size, void* d_ws, size_t ws_size,
                              hipStream_t stream) {
  const float* x     = (const float*)d_in[0]; // [96,48,512]
  const float* y     = (const float*)d_in[1]; // [96,64,64]
  const float* nItem = (const float*)d_in[2]; // [96]
  const float* Wp    = (const float*)d_in[3]; // [512,64]
  const float* W1    = (const float*)d_in[4]; // [64,128]
  const float* W2    = (const float*)d_in[5]; // [2,1]
  float* out = (float*)d_out;                 // [96,96,1]

  // workspace: gallery f32 (1,179,648 B) | pyf bf16 (1,572,864 B) | pxf bf16 (1,179,648 B)
  float* gallery = (float*)d_ws;
  unsigned short* pyf = (unsigned short*)((char*)d_ws + 1179648);
  unsigned short* pxf = (unsigned short*)((char*)d_ws + 1179648 + 1572864);

  hipLaunchKernelGGL(k_gallery, dim3(288), dim3(256), 0, stream, x, Wp, gallery);
  hipLaunchKernelGGL(k_pyf, dim3(768), dim3(256), 0, stream, y, W1, pyf);
  hipLaunchKernelGGL(k_pxf, dim3(576), dim3(256), 0, stream, gallery, W1, pxf);
  hipLaunchKernelGGL(k_att, dim3(2304), dim3(256), 0, stream, pyf, pxf, nItem, W2, out);
}

// Round 2
// 40.806 us; speedup vs baseline: 1.2088x; 1.2088x over previous
//
#include <hip/hip_runtime.h>
#include <hip/hip_bf16.h>

// ---------------------------------------------------------------------------
// scores[y,x] = sum_h W2[h] * ( sum_{m,n} leaky( py[y,h,m,:].px[x,h,n,:] /8 ) ) / (nItem[x]*64)
//   py = (Y @ W1) split heads          [96,2,64,64]
//   px = (gelu(X @ Wp) @ W1) heads     [96,2,48,64]
// All GEMMs on MFMA (bf16, f32 accum). Prep kernels emit py/px as bf16 MFMA
// fragment images; pairwise kernel is register-resident MFMA with 4x A-reuse.
// leaky(z) = 0.3 z + 0.7 relu(z); positive scales deferred to epilogue.
//
// Fragment map (A and B of mfma_f32_16x16x32_bf16, same map):
//   lane l holds (rc = l&15, k = 8*(l>>4)+i), i=0..7.
// C/D map: col(N) = l&15, row(M) = (l>>4)*4 + j.
// py image: [y][h][mt(4)][kc(2)][lane(64)][i(8)]
// px image: [x][h][nt(3)][kc(2)][lane(64)][i(8)]
// ---------------------------------------------------------------------------

typedef short bf16x8 __attribute__((ext_vector_type(8))); // 8 bf16 = 4 VGPRs
typedef float f32x4 __attribute__((ext_vector_type(4)));

__device__ __forceinline__ unsigned short f2bf(float v) {
  __hip_bfloat16 b = __float2bfloat16(v);
  return *reinterpret_cast<unsigned short*>(&b);
}

__device__ __forceinline__ bf16x8 load8_cvt(const float* __restrict__ p) {
  f32x4 v0 = *reinterpret_cast<const f32x4*>(p);
  f32x4 v1 = *reinterpret_cast<const f32x4*>(p + 4);
  bf16x8 r;
  r[0] = (short)f2bf(v0[0]); r[1] = (short)f2bf(v0[1]);
  r[2] = (short)f2bf(v0[2]); r[3] = (short)f2bf(v0[3]);
  r[4] = (short)f2bf(v1[0]); r[5] = (short)f2bf(v1[1]);
  r[6] = (short)f2bf(v1[2]); r[7] = (short)f2bf(v1[3]);
  return r;
}

// ---------------------------------------------------------------------------
// K0: weight fragment images. WpF: [kc16][nt4][lane][8] (64KB). W1F: [kc2][nt8][lane][8] (16KB).
// 160 blocks x 256 = 40960 threads, one element each; coalesced frag-order store.
// ---------------------------------------------------------------------------
__global__ __launch_bounds__(256) void k_wprep(const float* __restrict__ Wp,
                                               const float* __restrict__ W1,
                                               unsigned short* __restrict__ WpF,
                                               unsigned short* __restrict__ W1F) {
  int tid = blockIdx.x * 256 + threadIdx.x;
  if (tid < 32768) {
    int kc = tid >> 11, nt = (tid >> 9) & 3, l = (tid >> 3) & 63, i = tid & 7;
    int k = 32 * kc + 8 * (l >> 4) + i, c = nt * 16 + (l & 15);
    WpF[tid] = f2bf(Wp[k * 64 + c]);
  } else {
    int t2 = tid - 32768;
    int kc = t2 >> 12, nt = (t2 >> 9) & 7, l = (t2 >> 3) & 63, i = t2 & 7;
    int k = 32 * kc + 8 * (l >> 4) + i, d = nt * 16 + (l & 15);
    W1F[t2] = f2bf(W1[k * 128 + d]);
  }
}

// ---------------------------------------------------------------------------
// K1: py frag image. Wave per 16-row tile of Y[6144,64]; 96 blocks x 4 waves.
// 16 MFMA per wave; scalar ushort frag stores (32/lane).
// ---------------------------------------------------------------------------
__global__ __launch_bounds__(256) void k_py(const float* __restrict__ y,
                                            const unsigned short* __restrict__ W1F_u,
                                            unsigned short* __restrict__ pyf) {
  int lane = threadIdx.x & 63;
  int w = threadIdx.x >> 6;
  int T = blockIdx.x * 4 + w; // 0..383
  const bf16x8* W1F = reinterpret_cast<const bf16x8*>(W1F_u);
  const float* yb = y + (size_t)(T * 16 + (lane & 15)) * 64 + 8 * (lane >> 4);
  bf16x8 a0 = load8_cvt(yb);
  bf16x8 a1 = load8_cvt(yb + 32);
  f32x4 acc[8];
#pragma unroll
  for (int nt = 0; nt < 8; ++nt) acc[nt] = (f32x4){0.f, 0.f, 0.f, 0.f};
#pragma unroll
  for (int nt = 0; nt < 8; ++nt) {
    acc[nt] = __builtin_amdgcn_mfma_f32_16x16x32_bf16(a0, W1F[nt * 64 + lane], acc[nt], 0, 0, 0);
    acc[nt] = __builtin_amdgcn_mfma_f32_16x16x32_bf16(a1, W1F[(8 + nt) * 64 + lane], acc[nt], 0, 0, 0);
  }
  int r_hi = (lane >> 4) * 4;
#pragma unroll
  for (int nt = 0; nt < 8; ++nt) {
    int d = nt * 16 + (lane & 15);
    int h = d >> 6, dd = d & 63;
    int kc = dd >> 5, q = (dd >> 3) & 3, i = dd & 7;
#pragma unroll
    for (int j = 0; j < 4; ++j) {
      int row = T * 16 + r_hi + j;
      int yi = row >> 6, m = row & 63;
      int mt = m >> 4, rr = m & 15;
      size_t idx = ((size_t)((yi * 2 + h) * 8 + mt * 2 + kc)) * 512 + (rr + (q << 4)) * 8 + i;
      pyf[idx] = f2bf(acc[nt][j]);
    }
  }
}

// ---------------------------------------------------------------------------
// K2: fused gallery+px. Block = 4 waves on one 16-row tile of X[4608,512].
// Phase1: GEMM1 (K=512, split 4 waves x 4 kc) -> LDS reduce -> gelu ->
// LDS transpose (144B stride, conflict-free b128) -> Phase2: GEMM2 -> px frags.
// ---------------------------------------------------------------------------
__global__ __launch_bounds__(256) void k_gal_px(const float* __restrict__ x,
                                                const unsigned short* __restrict__ WpF_u,
                                                const unsigned short* __restrict__ W1F_u,
                                                unsigned short* __restrict__ pxf) {
  __shared__ float red[4 * 16 * 64];        // 16KB partials
  __shared__ unsigned short gal[16 * 72];   // 2.25KB, padded row stride 144B
  int lane = threadIdx.x & 63;
  int w = threadIdx.x >> 6;
  int rowbase = blockIdx.x * 16;
  const bf16x8* WpF = reinterpret_cast<const bf16x8*>(WpF_u);
  const bf16x8* W1F = reinterpret_cast<const bf16x8*>(W1F_u);
  const float* xb = x + (size_t)(rowbase + (lane & 15)) * 512 + 8 * (lane >> 4);

  f32x4 acc1[4];
#pragma unroll
  for (int nt = 0; nt < 4; ++nt) acc1[nt] = (f32x4){0.f, 0.f, 0.f, 0.f};
#pragma unroll
  for (int kk = 0; kk < 4; ++kk) {
    int kc = w * 4 + kk;
    bf16x8 a = load8_cvt(xb + 32 * kc);
#pragma unroll
    for (int nt = 0; nt < 4; ++nt)
      acc1[nt] = __builtin_amdgcn_mfma_f32_16x16x32_bf16(a, WpF[(kc * 4 + nt) * 64 + lane], acc1[nt], 0, 0, 0);
  }
#pragma unroll
  for (int nt = 0; nt < 4; ++nt)
#pragma unroll
    for (int j = 0; j < 4; ++j)
      red[(w * 16 + nt * 4 + j) * 64 + lane] = acc1[nt][j];
  __syncthreads();
  // wave w reduces column-block nt=w, gelu, transpose into gal
#pragma unroll
  for (int j = 0; j < 4; ++j) {
    float s = red[(0 * 16 + w * 4 + j) * 64 + lane] + red[(1 * 16 + w * 4 + j) * 64 + lane]
            + red[(2 * 16 + w * 4 + j) * 64 + lane] + red[(3 * 16 + w * 4 + j) * 64 + lane];
    float ge = 0.5f * s * (1.0f + erff(s * 0.70710678118654752f));
    int r = (lane >> 4) * 4 + j;
    int c = w * 16 + (lane & 15);
    gal[r * 72 + c] = f2bf(ge);
  }
  __syncthreads();
  // phase 2: gallery-tile A-frags from LDS
  const unsigned short* gp = &gal[(lane & 15) * 72 + 8 * (lane >> 4)];
  bf16x8 g0 = *reinterpret_cast<const bf16x8*>(gp);
  bf16x8 g1 = *reinterpret_cast<const bf16x8*>(gp + 32);
  f32x4 acc2[2];
  acc2[0] = (f32x4){0.f, 0.f, 0.f, 0.f};
  acc2[1] = (f32x4){0.f, 0.f, 0.f, 0.f};
#pragma unroll
  for (int u = 0; u < 2; ++u) {
    int nt = w * 2 + u;
    acc2[u] = __builtin_amdgcn_mfma_f32_16x16x32_bf16(g0, W1F[nt * 64 + lane], acc2[u], 0, 0, 0);
    acc2[u] = __builtin_amdgcn_mfma_f32_16x16x32_bf16(g1, W1F[(8 + nt) * 64 + lane], acc2[u], 0, 0, 0);
  }
#pragma unroll
  for (int u = 0; u < 2; ++u) {
    int nt = w * 2 + u;
    int d = nt * 16 + (lane & 15);
    int h = d >> 6, dd = d & 63;
    int kc = dd >> 5, q = (dd >> 3) & 3, i = dd & 7;
#pragma unroll
    for (int j = 0; j < 4; ++j) {
      int row = rowbase + (lane >> 4) * 4 + j;
      int xi = row / 48, n = row % 48;
      int nt3 = n >> 4, rr = n & 15;
      size_t idx = ((size_t)((xi * 2 + h) * 6 + nt3 * 2 + kc)) * 512 + (rr + (q << 4)) * 8 + i;
      pxf[idx] = f2bf(acc2[u][j]);
    }
  }
}

// ---------------------------------------------------------------------------
// K3: pairwise. Wave = (yi, 4 xi) with A-frags register-resident per head:
// 16KB/pair L2 traffic (was 28KB). Block = 4 waves, same yi, 16 xi. 576 blocks.
// ---------------------------------------------------------------------------
__global__ __launch_bounds__(256) void k_att(const unsigned short* __restrict__ pyf_u,
                                             const unsigned short* __restrict__ pxf_u,
                                             const float* __restrict__ nItem,
                                             const float* __restrict__ W2,
                                             float* __restrict__ out) {
  int lane = threadIdx.x & 63;
  int w = threadIdx.x >> 6;
  int yi = blockIdx.x / 6;
  int xib = (blockIdx.x % 6) * 16 + w * 4;
  const bf16x8* PA = reinterpret_cast<const bf16x8*>(pyf_u);
  const bf16x8* PB = reinterpret_cast<const bf16x8*>(pxf_u);
  float sv[4][2];
#pragma unroll
  for (int g = 0; g < 4; ++g) { sv[g][0] = 0.f; sv[g][1] = 0.f; }
#pragma unroll
  for (int h = 0; h < 2; ++h) {
    bf16x8 a[4][2];
    size_t ab = (size_t)(yi * 2 + h) * 512 + lane;
#pragma unroll
    for (int mt = 0; mt < 4; ++mt) {
      a[mt][0] = PA[ab + (mt * 2 + 0) * 64];
      a[mt][1] = PA[ab + (mt * 2 + 1) * 64];
    }
#pragma unroll
    for (int g = 0; g < 4; ++g) {
      size_t bb = (size_t)((xib + g) * 2 + h) * 384 + lane;
      bf16x8 b[3][2];
#pragma unroll
      for (int nt = 0; nt < 3; ++nt) {
        b[nt][0] = PB[bb + (nt * 2 + 0) * 64];
        b[nt][1] = PB[bb + (nt * 2 + 1) * 64];
      }
      float sz = 0.f, sr = 0.f;
#pragma unroll
      for (int nt = 0; nt < 3; ++nt)
#pragma unroll
        for (int mt = 0; mt < 4; ++mt) {
          f32x4 acc = {0.f, 0.f, 0.f, 0.f};
          acc = __builtin_amdgcn_mfma_f32_16x16x32_bf16(a[mt][0], b[nt][0], acc, 0, 0, 0);
          acc = __builtin_amdgcn_mfma_f32_16x16x32_bf16(a[mt][1], b[nt][1], acc, 0, 0, 0);
#pragma unroll
          for (int j = 0; j < 4; ++j) { sz += acc[j]; sr += fmaxf(acc[j], 0.f); }
        }
      sv[g][h] += 0.3f * sz + 0.7f * sr;
    }
  }
#pragma unroll
  for (int g = 0; g < 4; ++g)
#pragma unroll
    for (int h = 0; h < 2; ++h)
#pragma unroll
      for (int off = 32; off >= 1; off >>= 1)
        sv[g][h] += __shfl_xor(sv[g][h], off, 64);
  if (lane == 0) {
    float w2a = W2[0], w2b = W2[1];
#pragma unroll
    for (int g = 0; g < 4; ++g) {
      int xi = xib + g;
      out[yi * 96 + xi] = (sv[g][0] * w2a + sv[g][1] * w2b) / (512.0f * nItem[xi]);
    }
  }
}

// ---------------------------------------------------------------------------
extern "C" void kernel_launch(void* const* d_in, const int* in_sizes, int n_in,
                              void* d_out, int out_size, void* d_ws, size_t ws_size,
                              hipStream_t stream) {
  const float* x     = (const float*)d_in[0]; // [96,48,512]
  const float* y     = (const float*)d_in[1]; // [96,64,64]
  const float* nItem = (const float*)d_in[2]; // [96]
  const float* Wp    = (const float*)d_in[3]; // [512,64]
  const float* W1    = (const float*)d_in[4]; // [64,128]
  const float* W2    = (const float*)d_in[5]; // [2,1]
  float* out = (float*)d_out;                 // [96,96,1]

  unsigned short* WpF = (unsigned short*)d_ws;   // 32768 elems (64KB)
  unsigned short* W1F = WpF + 32768;             // 8192 elems (16KB)
  unsigned short* pyf = W1F + 8192;              // 786432 elems (1.5MB)
  unsigned short* pxf = pyf + 786432;            // 589824 elems (1.125MB)

  hipLaunchKernelGGL(k_wprep, dim3(160), dim3(256), 0, stream, Wp, W1, WpF, W1F);
  hipLaunchKernelGGL(k_py, dim3(96), dim3(256), 0, stream, y, W1F, pyf);
  hipLaunchKernelGGL(k_gal_px, dim3(288), dim3(256), 0, stream, x, WpF, W1F, pxf);
  hipLaunchKernelGGL(k_att, dim3(576), dim3(256), 0, stream, pyf, pxf, nItem, W2, out);
}

// Round 3
// 34.894 us; speedup vs baseline: 1.4136x; 1.1694x over previous
//
#include <hip/hip_runtime.h>
#include <hip/hip_bf16.h>

// ---------------------------------------------------------------------------
// scores[y,x] = sum_h W2[h] * ( sum_{m,n} leaky( py[y,h,m,:].px[x,h,n,:] /8 ) ) / (nItem[x]*64)
//   py = (Y @ W1) split heads          [96,2,64,64]
//   px = (gelu(X @ Wp) @ W1) heads     [96,2,48,64]
// 2-kernel structure:
//   K1 (168 blocks): blocks 0..71 = fused gallery+px (64 x-rows each, Wp/W1
//       frag images self-built in LDS); blocks 72..167 = py (one yi each,
//       W1 frag image self-built in LDS). All MFMA, bf16 in / f32 acc.
//   K2 (576 blocks): pairwise leaky-reduce. Block = 4yi x 4xi; wave = 1 yi,
//       A-frags (both heads) register-resident; B shared across waves via L1.
// leaky(z)=0.3z+0.7relu(z); positive scales + W2 folded into epilogue FMAs.
//
// Fragment map (A and B of mfma_f32_16x16x32_bf16, same map):
//   lane l holds (rc = l&15, k = 8*(l>>4)+i), i=0..7.   C/D: col=l&15, row=(l>>4)*4+j.
// py image: [y][h][mt(4)][kc(2)][lane(64)][i(8)]
// px image: [x][h][nt(3)][kc(2)][lane(64)][i(8)]
// ---------------------------------------------------------------------------

typedef short bf16x8 __attribute__((ext_vector_type(8))); // 8 bf16 = 4 VGPRs
typedef float f32x4 __attribute__((ext_vector_type(4)));

__device__ __forceinline__ unsigned short f2bf(float v) {
  __hip_bfloat16 b = __float2bfloat16(v);
  return *reinterpret_cast<unsigned short*>(&b);
}

__device__ __forceinline__ bf16x8 load8_cvt(const float* __restrict__ p) {
  f32x4 v0 = *reinterpret_cast<const f32x4*>(p);
  f32x4 v1 = *reinterpret_cast<const f32x4*>(p + 4);
  bf16x8 r;
  r[0] = (short)f2bf(v0[0]); r[1] = (short)f2bf(v0[1]);
  r[2] = (short)f2bf(v0[2]); r[3] = (short)f2bf(v0[3]);
  r[4] = (short)f2bf(v1[0]); r[5] = (short)f2bf(v1[1]);
  r[6] = (short)f2bf(v1[2]); r[7] = (short)f2bf(v1[3]);
  return r;
}

// ---------------------------------------------------------------------------
// K1: fused prep. LDS: w1f 16KB | wpf-half 32KB | gal 4x(16x72) 9KB = 57.25KB.
// ---------------------------------------------------------------------------
__global__ __launch_bounds__(256) void k_prep(const float* __restrict__ x,
                                              const float* __restrict__ y,
                                              const float* __restrict__ Wp,
                                              const float* __restrict__ W1,
                                              unsigned short* __restrict__ pyf,
                                              unsigned short* __restrict__ pxf) {
  __shared__ unsigned short w1f[8192];      // frag f=kc*8+nt: [f][lane][8]
  __shared__ unsigned short wpf[16384];     // half: frag g=kcl*4+nt: [g][lane][8]
  __shared__ unsigned short gal[4][1152];   // per-wave 16 x 72 (padded)
  int t = threadIdx.x;
  int lane = t & 63, w = t >> 6;

  // build W1F (coalesced W1 read -> LDS scatter); both task types need it
#pragma unroll
  for (int it = 0; it < 32; ++it) {
    int idx = it * 256 + t;                  // over 64*128
    int k = idx >> 7, d = idx & 127;
    int l = (d & 15) + 16 * ((k >> 3) & 3);
    int f = (k >> 5) * 8 + (d >> 4);
    w1f[f * 512 + l * 8 + (k & 7)] = f2bf(W1[idx]);
  }

  if (blockIdx.x >= 72) {
    // ------------------------- py task: yi = blockIdx-72 -------------------
    __syncthreads();
    int yi = blockIdx.x - 72;
    const bf16x8* WF = reinterpret_cast<const bf16x8*>(w1f);
    int row0 = yi * 64 + w * 16 + (lane & 15);
    const float* yb = y + (size_t)row0 * 64 + 8 * (lane >> 4);
    bf16x8 a0 = load8_cvt(yb);
    bf16x8 a1 = load8_cvt(yb + 32);
    f32x4 acc[8];
#pragma unroll
    for (int nt = 0; nt < 8; ++nt) acc[nt] = (f32x4){0.f, 0.f, 0.f, 0.f};
#pragma unroll
    for (int nt = 0; nt < 8; ++nt) {
      acc[nt] = __builtin_amdgcn_mfma_f32_16x16x32_bf16(a0, WF[nt * 64 + lane], acc[nt], 0, 0, 0);
      acc[nt] = __builtin_amdgcn_mfma_f32_16x16x32_bf16(a1, WF[(8 + nt) * 64 + lane], acc[nt], 0, 0, 0);
    }
    int r_hi = (lane >> 4) * 4;
#pragma unroll
    for (int nt = 0; nt < 8; ++nt) {
      int d = nt * 16 + (lane & 15);
      int h = d >> 6, dd = d & 63;
      int kc = dd >> 5, q = (dd >> 3) & 3, i = dd & 7;
#pragma unroll
      for (int j = 0; j < 4; ++j) {
        int m = w * 16 + r_hi + j;           // row within yi
        int mt = m >> 4, rr = m & 15;
        size_t idx = ((size_t)((yi * 2 + h) * 8 + mt * 2 + kc)) * 512 + (rr + (q << 4)) * 8 + i;
        pyf[idx] = f2bf(acc[nt][j]);
      }
    }
  } else {
    // --------------------- gallery+px task: 64 rows of x -------------------
    int rowbase = blockIdx.x * 64;
    // build WpF half 0 (k = 0..255), coalesced Wp read -> LDS scatter
#pragma unroll
    for (int it = 0; it < 64; ++it) {
      int idx = it * 256 + t;                // over 256*64
      int k = idx >> 6, c = idx & 63;
      int l = (c & 15) + 16 * ((k >> 3) & 3);
      int g = ((k >> 5) & 7) * 4 + (c >> 4);
      wpf[g * 512 + l * 8 + (k & 7)] = f2bf(Wp[idx]);
    }
    __syncthreads();
    const bf16x8* WPF = reinterpret_cast<const bf16x8*>(wpf);
    const bf16x8* WF = reinterpret_cast<const bf16x8*>(w1f);
    int rloc = rowbase + w * 16 + (lane & 15);
    const float* xb = x + (size_t)rloc * 512 + 8 * (lane >> 4);
    f32x4 acc1[4];
#pragma unroll
    for (int nt = 0; nt < 4; ++nt) acc1[nt] = (f32x4){0.f, 0.f, 0.f, 0.f};
#pragma unroll
    for (int kc = 0; kc < 8; ++kc) {          // K 0..255
      bf16x8 a = load8_cvt(xb + 32 * kc);
#pragma unroll
      for (int nt = 0; nt < 4; ++nt)
        acc1[nt] = __builtin_amdgcn_mfma_f32_16x16x32_bf16(a, WPF[(kc * 4 + nt) * 64 + lane], acc1[nt], 0, 0, 0);
    }
    __syncthreads();                          // all waves done with half 0
    // rebuild WpF with half 1 (k = 256..511)
#pragma unroll
    for (int it = 0; it < 64; ++it) {
      int idx = it * 256 + t;
      int k = idx >> 6, c = idx & 63;
      int l = (c & 15) + 16 * ((k >> 3) & 3);
      int g = ((k >> 5) & 7) * 4 + (c >> 4);
      wpf[g * 512 + l * 8 + (k & 7)] = f2bf(Wp[16384 + idx]);
    }
    __syncthreads();
#pragma unroll
    for (int kc = 0; kc < 8; ++kc) {          // K 256..511
      bf16x8 a = load8_cvt(xb + 256 + 32 * kc);
#pragma unroll
      for (int nt = 0; nt < 4; ++nt)
        acc1[nt] = __builtin_amdgcn_mfma_f32_16x16x32_bf16(a, WPF[(kc * 4 + nt) * 64 + lane], acc1[nt], 0, 0, 0);
    }
    // gelu -> own-wave gal tile (no barrier needed: same-wave ds RAW)
#pragma unroll
    for (int nt = 0; nt < 4; ++nt)
#pragma unroll
      for (int j = 0; j < 4; ++j) {
        float s = acc1[nt][j];
        float ge = 0.5f * s * (1.0f + erff(s * 0.70710678118654752f));
        int rl = (lane >> 4) * 4 + j;
        int c = nt * 16 + (lane & 15);
        gal[w][rl * 72 + c] = f2bf(ge);
      }
    // phase 2: GEMM2 from own gal tile
    const unsigned short* gp = &gal[w][(lane & 15) * 72 + 8 * (lane >> 4)];
    bf16x8 g0 = *reinterpret_cast<const bf16x8*>(gp);
    bf16x8 g1 = *reinterpret_cast<const bf16x8*>(gp + 32);
    f32x4 acc2[8];
#pragma unroll
    for (int nt = 0; nt < 8; ++nt) acc2[nt] = (f32x4){0.f, 0.f, 0.f, 0.f};
#pragma unroll
    for (int nt = 0; nt < 8; ++nt) {
      acc2[nt] = __builtin_amdgcn_mfma_f32_16x16x32_bf16(g0, WF[nt * 64 + lane], acc2[nt], 0, 0, 0);
      acc2[nt] = __builtin_amdgcn_mfma_f32_16x16x32_bf16(g1, WF[(8 + nt) * 64 + lane], acc2[nt], 0, 0, 0);
    }
    int r_hi = (lane >> 4) * 4;
#pragma unroll
    for (int nt = 0; nt < 8; ++nt) {
      int d = nt * 16 + (lane & 15);
      int h = d >> 6, dd = d & 63;
      int kc = dd >> 5, q = (dd >> 3) & 3, i = dd & 7;
#pragma unroll
      for (int j = 0; j < 4; ++j) {
        int row = rowbase + w * 16 + r_hi + j;
        int xi = row / 48, n = row % 48;
        int nt3 = n >> 4, rr = n & 15;
        size_t idx = ((size_t)((xi * 2 + h) * 6 + nt3 * 2 + kc)) * 512 + (rr + (q << 4)) * 8 + i;
        pxf[idx] = f2bf(acc2[nt][j]);
      }
    }
  }
}

// ---------------------------------------------------------------------------
// K2: pairwise. 576 blocks = 24 yb x 24 xb; block = 4yi x 4xi; wave = 1 yi.
// A (both heads) register-resident; zero4 C-operand hoisted via opaque asm;
// epilogue: szw += acc*(0.3*W2h), srw += relu(acc)*(0.7*W2h) (pk_fma-able).
// ---------------------------------------------------------------------------
__global__ __launch_bounds__(256) void k_att(const unsigned short* __restrict__ pyf_u,
                                             const unsigned short* __restrict__ pxf_u,
                                             const float* __restrict__ nItem,
                                             const float* __restrict__ W2,
                                             float* __restrict__ out) {
  int lane = threadIdx.x & 63;
  int w = threadIdx.x >> 6;
  int yi = (blockIdx.x / 24) * 4 + w;
  int xb = (blockIdx.x % 24) * 4;
  const bf16x8* PA = reinterpret_cast<const bf16x8*>(pyf_u);
  const bf16x8* PB = reinterpret_cast<const bf16x8*>(pxf_u);

  f32x4 zero4 = {0.f, 0.f, 0.f, 0.f};
  asm volatile("" : "+v"(zero4));            // pin zero C-operand in 4 VGPRs

  bf16x8 a[16];                              // both heads: a[h*8 + mt*2 + kc]
  size_t abase = (size_t)(yi * 2) * 512 + lane;
#pragma unroll
  for (int f = 0; f < 8; ++f) {
    a[f]     = PA[abase + f * 64];
    a[8 + f] = PA[abase + 512 + f * 64];
  }
  float w2h0 = W2[0], w2h1 = W2[1];
  float res[4];
#pragma unroll
  for (int g = 0; g < 4; ++g) {
    int xi = xb + g;
    f32x4 szw = {0.f, 0.f, 0.f, 0.f};
    f32x4 srw = {0.f, 0.f, 0.f, 0.f};
#pragma unroll
    for (int h = 0; h < 2; ++h) {
      size_t bbase = (size_t)((xi * 2 + h) * 6) * 64 + lane;
      bf16x8 b[6];
#pragma unroll
      for (int f = 0; f < 6; ++f) b[f] = PB[bbase + f * 64];
      float c3 = 0.3f * (h ? w2h1 : w2h0);
      float c7 = 0.7f * (h ? w2h1 : w2h0);
#pragma unroll
      for (int nt = 0; nt < 3; ++nt)
#pragma unroll
        for (int mt = 0; mt < 4; ++mt) {
          f32x4 acc = __builtin_amdgcn_mfma_f32_16x16x32_bf16(a[h * 8 + mt * 2], b[nt * 2], zero4, 0, 0, 0);
          acc = __builtin_amdgcn_mfma_f32_16x16x32_bf16(a[h * 8 + mt * 2 + 1], b[nt * 2 + 1], acc, 0, 0, 0);
          f32x4 mx = {fmaxf(acc[0], 0.f), fmaxf(acc[1], 0.f), fmaxf(acc[2], 0.f), fmaxf(acc[3], 0.f)};
          szw += acc * c3;
          srw += mx * c7;
        }
    }
    f32x4 t4 = szw + srw;
    float tot = (t4[0] + t4[1]) + (t4[2] + t4[3]);
#pragma unroll
    for (int off = 32; off >= 1; off >>= 1) tot += __shfl_xor(tot, off, 64);
    res[g] = tot;
  }
  if (lane == 0) {
#pragma unroll
    for (int g = 0; g < 4; ++g) {
      int xi = xb + g;
      out[yi * 96 + xi] = res[g] / (512.0f * nItem[xi]);
    }
  }
}

// ---------------------------------------------------------------------------
extern "C" void kernel_launch(void* const* d_in, const int* in_sizes, int n_in,
                              void* d_out, int out_size, void* d_ws, size_t ws_size,
                              hipStream_t stream) {
  const float* x     = (const float*)d_in[0]; // [96,48,512]
  const float* y     = (const float*)d_in[1]; // [96,64,64]
  const float* nItem = (const float*)d_in[2]; // [96]
  const float* Wp    = (const float*)d_in[3]; // [512,64]
  const float* W1    = (const float*)d_in[4]; // [64,128]
  const float* W2    = (const float*)d_in[5]; // [2,1]
  float* out = (float*)d_out;                 // [96,96,1]

  unsigned short* pyf = (unsigned short*)d_ws;   // 786432 elems (1.5MB)
  unsigned short* pxf = pyf + 786432;            // 589824 elems (1.125MB)

  hipLaunchKernelGGL(k_prep, dim3(168), dim3(256), 0, stream, x, y, Wp, W1, pyf, pxf);
  hipLaunchKernelGGL(k_att, dim3(576), dim3(256), 0, stream, pyf, pxf, nItem, W2, out);
}